// Round 16
// baseline (185.169 us; speedup 1.0000x reference)
//
#include <hip/hip_runtime.h>

typedef _Float16 f16x8 __attribute__((ext_vector_type(8)));
typedef _Float16 f16x4 __attribute__((ext_vector_type(4)));
typedef float  f32x4  __attribute__((ext_vector_type(4)));
typedef unsigned int u32x4 __attribute__((ext_vector_type(4)));
typedef unsigned int u32x2 __attribute__((ext_vector_type(2)));

#define MFMA32F __builtin_amdgcn_mfma_f32_16x16x32_f16

// K=16 f16 MFMA, hazard-safe
__device__ __forceinline__ f32x4 mfma_k16(const f16x4& a, const f16x4& b, f32x4 c){
#if __has_builtin(__builtin_amdgcn_mfma_f32_16x16x16f16)
    return __builtin_amdgcn_mfma_f32_16x16x16f16(a, b, c, 0, 0, 0);
#else
    asm volatile("s_nop 1\n\t"
                 "v_mfma_f32_16x16x16_f16 %0, %1, %2, %0\n\t"
                 "s_nop 7\n\t"
                 "s_nop 7"
                 : "+v"(c)
                 : "v"(__builtin_bit_cast(u32x2, a)), "v"(__builtin_bit_cast(u32x2, b)));
    return c;
#endif
}

// ---- d_ws fragment-image layout (byte offsets; lane-major 16B/8B rows) ----
#define OFF_W1AF 0
#define OFF_W1BF 4096
#define OFF_W2TF 8192
#define OFF_W3TF 16384
#define OFF_W1OF 20480
#define OFF_W2OF 28672
#define OFF_W3OF 36864
#define OFF_B1V  40960

// ---- LDS layout (per batch-element half) ----
// short indices:
#define XT_S 0        // Xt[60][40] f16 (cols 30..39 zero)
#define A_S  2400     // A[64][72] f16 (col60=1.0-carry, rows 60..63=0)
#define B_S  7008     // B[64][72] f16
// float indices:
#define EB_F 5808     // Ebar[60][20] f32
#define O_F  7008     // O[24] f32
#define NSH  14064    // shorts per half (28128 B); total 2x = 56256 B

__device__ __forceinline__ unsigned short hbits(float x){ return __builtin_bit_cast(unsigned short, (_Float16)x); }

__device__ __forceinline__ f16x8 addrelu16(u32x4 a, u32x4 b){
    f16x8 s = __builtin_bit_cast(f16x8, a) + __builtin_bit_cast(f16x8, b);
    const f16x8 z = {};
    return __builtin_elementwise_max(s, z);
}

__device__ __forceinline__ f16x4 relupack16(const f32x4& d){
    u32x2 u;
    u[0] = __builtin_bit_cast(unsigned int, __builtin_amdgcn_cvt_pkrtz(d[0], d[1]));
    u[1] = __builtin_bit_cast(unsigned int, __builtin_amdgcn_cvt_pkrtz(d[2], d[3]));
    const f16x4 z = {};
    return __builtin_elementwise_max(__builtin_bit_cast(f16x4, u), z);
}

// ---- prep kernel: materialize all weight fragments once (1 block x 64 threads) ----
__global__ void prep_kernel(const float* __restrict__ fr_w1, const float* __restrict__ fr_b1,
                            const float* __restrict__ fr_w2, const float* __restrict__ fr_b2,
                            const float* __restrict__ fr_w3, const float* __restrict__ fr_b3,
                            const float* __restrict__ fo_w1, const float* __restrict__ fo_b1,
                            const float* __restrict__ fo_w2, const float* __restrict__ fo_b2,
                            const float* __restrict__ fo_w3, const float* __restrict__ fo_b3,
                            void* __restrict__ wsv)
{
    const int l = threadIdx.x;
    if (l >= 64) return;
    const int lane15 = l & 15, g4 = (l >> 4) & 3;
    unsigned short* ws = (unsigned short*)wsv;

    for (int n = 0; n < 4; ++n){
        const int col = n * 16 + lane15;
        const bool cvv = col < 60;
        for (int j = 0; j < 8; ++j){
            const int f = g4 * 8 + j;
            ws[OFF_W1AF/2 + (n*64+l)*8 + j] = hbits((f < 30 && cvv) ? fr_w1[f*60+col] : 0.f);
            ws[OFF_W1BF/2 + (n*64+l)*8 + j] = hbits((f < 30 && cvv) ? fr_w1[(30+f)*60+col] : 0.f);
        }
    }
    for (int m = 0; m < 4; ++m){
        const int row = m * 16 + lane15;
        for (int c2 = 0; c2 < 2; ++c2)
            for (int j = 0; j < 8; ++j){
                const int k = c2*32 + g4*8 + j;
                float v = 0.f;
                if (row < 60)       v = (k < 60) ? fr_w2[k*60+row] : (k == 60 ? fr_b2[row] : 0.f);
                else if (row == 60) v = (k == 60) ? 1.f : 0.f;
                ws[OFF_W2TF/2 + ((m*2+c2)*64+l)*8 + j] = hbits(v);
            }
    }
    for (int m2 = 0; m2 < 2; ++m2){
        const int e = m2 * 16 + lane15;
        for (int c = 0; c < 4; ++c)
            for (int j = 0; j < 4; ++j){
                const int k = c*16 + g4*4 + j;
                float v = 0.f;
                if (e < 20) v = (k < 60) ? fr_w3[k*20+e] : (k == 60 ? fr_b3[e] : 0.f);
                ws[OFF_W3TF/2 + ((m2*4+c)*64+l)*4 + j] = hbits(v);
            }
    }
    for (int m = 0; m < 4; ++m){
        const int h = m * 16 + lane15;
        for (int c2 = 0; c2 < 2; ++c2)
            for (int j = 0; j < 8; ++j){
                const int k = c2*32 + g4*8 + j;
                float v = 0.f;
                if (h < 60)       v = (k < 50) ? fo_w1[k*60+h] : (k == 50 ? fo_b1[h] : 0.f);
                else if (h == 60) v = (k == 50) ? 1.f : 0.f;
                ws[OFF_W1OF/2 + ((m*2+c2)*64+l)*8 + j] = hbits(v);
            }
    }
    for (int m = 0; m < 4; ++m){
        const int h2 = m * 16 + lane15;
        for (int c = 0; c < 4; ++c)
            for (int j = 0; j < 4; ++j){
                const int k = c*16 + g4*4 + j;
                float v = 0.f;
                if (h2 < 60)       v = (k < 60) ? fo_w2[k*60+h2] : (k == 60 ? fo_b2[h2] : 0.f);
                else if (h2 == 60) v = (k == 60) ? 1.f : 0.f;
                ws[OFF_W2OF/2 + ((m*4+c)*64+l)*4 + j] = hbits(v);
            }
    }
    for (int m2 = 0; m2 < 2; ++m2){
        const int o = m2 * 16 + lane15;
        for (int c = 0; c < 4; ++c)
            for (int j = 0; j < 4; ++j){
                const int k = c*16 + g4*4 + j;
                float v = 0.f;
                if (o < 24) v = (k < 60) ? fo_w3[k*24+o] : (k == 60 ? fo_b3[o] : 0.f);
                ws[OFF_W3OF/2 + ((m2*4+c)*64+l)*4 + j] = hbits(v);
            }
    }
    float* wb = (float*)((char*)wsv + OFF_B1V);
    for (int n = 0; n < 4; ++n){
        const int col = n * 16 + lane15;
        wb[l*4 + n] = (col < 60) ? fr_b1[col] : ((col == 60) ? 1.0f : 0.0f);
    }
}

__global__ __launch_bounds__(512, 3)
void innet_kernel(const float* __restrict__ x, const void* __restrict__ wsv,
                  float* __restrict__ out, int Btot)
{
    __shared__ __align__(16) unsigned short ss_all[2 * NSH];
    const int tid0   = threadIdx.x;
    const int half   = tid0 >> 8;            // which batch element of the pair
    const int tid    = tid0 & 255;
    unsigned short* ss = ss_all + half * NSH;
    float* sf = (float*)ss;

    const int b      = blockIdx.x * 2 + half;
    const int lane15 = tid & 15;
    const int g4     = (tid >> 4) & 3;
    const int w      = tid >> 6;
    const int l64    = tid & 63;
    const char* wsb  = (const char*)wsv;
    const bool live  = (b < Btot);

    // ---- phase 0 ----
    const float* xb = x + (size_t)b * 1800;
    if (live){
        for (int i = tid; i < 1800; i += 256){
            const int f = i / 60, p = i - f * 60;
            ss[XT_S + p * 40 + f] = hbits(xb[i]);
        }
    } else {
        for (int i = tid; i < 1800; i += 256){
            const int f = i / 60, p = i - f * 60;
            ss[XT_S + p * 40 + f] = 0;
        }
    }
    for (int i = tid; i < 600; i += 256){
        const int p = i / 10;
        ss[XT_S + p * 40 + 30 + (i - p * 10)] = 0;
    }
    for (int i = tid; i < 576; i += 256){
        const int arr = i / 288, rem = i - arr * 288;
        ss[(arr ? B_S : A_S) + 60 * 72 + rem] = 0;
    }
    for (int i = tid; i < 1200; i += 256) sf[EB_F + i] = 0.f;
    if (tid < 24) sf[O_F + tid] = 0.f;
    __syncthreads();

    // ---- phase 1: A/B panels via MFMA ----
    {
        f16x8 w1af[4], w1bf[4];
        #pragma unroll
        for (int n = 0; n < 4; ++n){
            w1af[n] = *(const f16x8*)(wsb + OFF_W1AF + (n*64 + l64)*16);
            w1bf[n] = *(const f16x8*)(wsb + OFF_W1BF + (n*64 + l64)*16);
        }
        const f32x4 b1v = *(const f32x4*)(wsb + OFF_B1V + l64*16);
        const int pr_ = w * 16 + lane15;
        const u32x4 ux = *(const u32x4*)&ss[XT_S + pr_ * 40 + g4 * 8];
        const f16x8 xa = __builtin_bit_cast(f16x8, ux);
        const f32x4 z = {0.f, 0.f, 0.f, 0.f};
        f32x4 aA0 = MFMA32F(xa, w1af[0], z, 0, 0, 0);
        f32x4 aA1 = MFMA32F(xa, w1af[1], z, 0, 0, 0);
        f32x4 aA2 = MFMA32F(xa, w1af[2], z, 0, 0, 0);
        f32x4 aA3 = MFMA32F(xa, w1af[3], z, 0, 0, 0);
        f32x4 aB0 = MFMA32F(xa, w1bf[0], z, 0, 0, 0);
        f32x4 aB1 = MFMA32F(xa, w1bf[1], z, 0, 0, 0);
        f32x4 aB2 = MFMA32F(xa, w1bf[2], z, 0, 0, 0);
        f32x4 aB3 = MFMA32F(xa, w1bf[3], z, 0, 0, 0);
        #pragma unroll
        for (int reg = 0; reg < 4; ++reg){
            const int p = w * 16 + g4 * 4 + reg;
            if (p < 60){
                ss[A_S + p * 72 +      lane15] = hbits(aA0[reg] + b1v[0]);
                ss[A_S + p * 72 + 16 + lane15] = hbits(aA1[reg] + b1v[1]);
                ss[A_S + p * 72 + 32 + lane15] = hbits(aA2[reg] + b1v[2]);
                ss[A_S + p * 72 + 48 + lane15] = hbits(aA3[reg] + b1v[3]);
                ss[B_S + p * 72 +      lane15] = hbits(aB0[reg]);
                ss[B_S + p * 72 + 16 + lane15] = hbits(aB1[reg]);
                ss[B_S + p * 72 + 32 + lane15] = hbits(aB2[reg]);
                ss[B_S + p * 72 + 48 + lane15] = hbits(aB3[reg]);
            }
        }
    }
    __syncthreads();

    // ---- phase 2: swapped register chain. wave-of-half w owns receivers r = w, w+4, ... ----
    {
        f16x8 w2tf[4][2];
        #pragma unroll
        for (int m = 0; m < 4; ++m)
            #pragma unroll
            for (int c2 = 0; c2 < 2; ++c2)
                w2tf[m][c2] = *(const f16x8*)(wsb + OFF_W2TF + ((m*2+c2)*64 + l64)*16);
        f16x4 w3tf[2][4];
        #pragma unroll
        for (int m2 = 0; m2 < 2; ++m2)
            #pragma unroll
            for (int c = 0; c < 4; ++c)
                w3tf[m2][c] = *(const f16x4*)(wsb + OFF_W3TF + ((m2*4+c)*64 + l64)*8);

        #pragma unroll 1
        for (int r = w; r < 60; r += 4){
            const u32x4 a0 = *(const u32x4*)&ss[A_S + r * 72 + g4 * 8];
            const u32x4 a1 = *(const u32x4*)&ss[A_S + r * 72 + 32 + g4 * 8];
            f32x4 acc0 = {0.f,0.f,0.f,0.f}, acc1 = {0.f,0.f,0.f,0.f};
            #pragma unroll
            for (int st = 0; st < 4; ++st){
                const int s = st * 16 + lane15;
                const u32x4 bb0 = *(const u32x4*)&ss[B_S + s * 72 + g4 * 8];
                const u32x4 bb1 = *(const u32x4*)&ss[B_S + s * 72 + 32 + g4 * 8];
                const f16x8 h0 = addrelu16(a0, bb0);
                const f16x8 h1 = addrelu16(a1, bb1);
                f32x4 d0 = {0.f,0.f,0.f,0.f}, d1 = {0.f,0.f,0.f,0.f};
                f32x4 d2 = {0.f,0.f,0.f,0.f}, d3 = {0.f,0.f,0.f,0.f};
                d0 = MFMA32F(w2tf[0][0], h0, d0, 0,0,0); d0 = MFMA32F(w2tf[0][1], h1, d0, 0,0,0);
                d1 = MFMA32F(w2tf[1][0], h0, d1, 0,0,0); d1 = MFMA32F(w2tf[1][1], h1, d1, 0,0,0);
                d2 = MFMA32F(w2tf[2][0], h0, d2, 0,0,0); d2 = MFMA32F(w2tf[2][1], h1, d2, 0,0,0);
                d3 = MFMA32F(w2tf[3][0], h0, d3, 0,0,0); d3 = MFMA32F(w2tf[3][1], h1, d3, 0,0,0);
                const f16x4 hb0 = relupack16(d0), hb1 = relupack16(d1);
                const f16x4 hb2 = relupack16(d2), hb3 = relupack16(d3);
                f32x4 e0 = {0.f,0.f,0.f,0.f}, e1 = {0.f,0.f,0.f,0.f};
                e0 = mfma_k16(w3tf[0][0], hb0, e0); e0 = mfma_k16(w3tf[0][1], hb1, e0);
                e0 = mfma_k16(w3tf[0][2], hb2, e0); e0 = mfma_k16(w3tf[0][3], hb3, e0);
                e1 = mfma_k16(w3tf[1][0], hb0, e1); e1 = mfma_k16(w3tf[1][1], hb1, e1);
                e1 = mfma_k16(w3tf[1][2], hb2, e1); e1 = mfma_k16(w3tf[1][3], hb3, e1);
                const float vm = (s < 60 && s != r) ? 1.f : 0.f;
                #pragma unroll
                for (int reg = 0; reg < 4; ++reg){
                    acc0[reg] += vm * fmaxf(e0[reg], 0.f);
                    acc1[reg] += vm * fmaxf(e1[reg], 0.f);
                }
            }
            #pragma unroll
            for (int reg = 0; reg < 4; ++reg){
                float v0 = acc0[reg];
                v0 += __shfl_xor(v0, 1); v0 += __shfl_xor(v0, 2);
                v0 += __shfl_xor(v0, 4); v0 += __shfl_xor(v0, 8);
                float v1 = acc1[reg];
                v1 += __shfl_xor(v1, 1); v1 += __shfl_xor(v1, 2);
                v1 += __shfl_xor(v1, 4); v1 += __shfl_xor(v1, 8);
                if (lane15 == 0){
                    sf[EB_F + r * 20 + g4 * 4 + reg] += v0;
                    const int e1i = 16 + g4 * 4 + reg;
                    if (e1i < 20) sf[EB_F + r * 20 + e1i] += v1;
                }
            }
        }
    }
    __syncthreads();

    // ---- phase 5: output MLP, swapped chain ----
    {
        const int p5 = w * 16 + lane15;
        const int pe = (p5 < 60) ? p5 : 0;
        const u32x4 uc0 = *(const u32x4*)&ss[XT_S + pe * 40 + g4 * 8];
        f16x8 cb0 = __builtin_bit_cast(f16x8, uc0);
        if (g4 == 3){
            cb0[6] = (_Float16)sf[EB_F + pe * 20 + 0];
            cb0[7] = (_Float16)sf[EB_F + pe * 20 + 1];
        }
        f16x8 cb1;
        #pragma unroll
        for (int j = 0; j < 8; ++j){
            const int k = 32 + g4 * 8 + j;
            float v;
            if (k < 50) v = sf[EB_F + pe * 20 + (k - 30)];
            else        v = (k == 50) ? 1.f : 0.f;
            cb1[j] = (_Float16)v;
        }
        f16x8 w1of[4][2];
        #pragma unroll
        for (int m = 0; m < 4; ++m)
            #pragma unroll
            for (int c2 = 0; c2 < 2; ++c2)
                w1of[m][c2] = *(const f16x8*)(wsb + OFF_W1OF + ((m*2+c2)*64 + l64)*16);
        f32x4 d0 = {0.f,0.f,0.f,0.f}, d1 = {0.f,0.f,0.f,0.f};
        f32x4 d2 = {0.f,0.f,0.f,0.f}, d3 = {0.f,0.f,0.f,0.f};
        d0 = MFMA32F(w1of[0][0], cb0, d0, 0,0,0); d0 = MFMA32F(w1of[0][1], cb1, d0, 0,0,0);
        d1 = MFMA32F(w1of[1][0], cb0, d1, 0,0,0); d1 = MFMA32F(w1of[1][1], cb1, d1, 0,0,0);
        d2 = MFMA32F(w1of[2][0], cb0, d2, 0,0,0); d2 = MFMA32F(w1of[2][1], cb1, d2, 0,0,0);
        d3 = MFMA32F(w1of[3][0], cb0, d3, 0,0,0); d3 = MFMA32F(w1of[3][1], cb1, d3, 0,0,0);
        const f16x4 hb0 = relupack16(d0), hb1 = relupack16(d1);
        const f16x4 hb2 = relupack16(d2), hb3 = relupack16(d3);
        __builtin_amdgcn_sched_barrier(0);
        f16x4 w2of[4][4];
        #pragma unroll
        for (int m = 0; m < 4; ++m)
            #pragma unroll
            for (int c = 0; c < 4; ++c)
                w2of[m][c] = *(const f16x4*)(wsb + OFF_W2OF + ((m*4+c)*64 + l64)*8);
        f32x4 g0 = {0.f,0.f,0.f,0.f}, g1 = {0.f,0.f,0.f,0.f};
        f32x4 g2 = {0.f,0.f,0.f,0.f}, g3 = {0.f,0.f,0.f,0.f};
        g0 = mfma_k16(w2of[0][0], hb0, g0); g0 = mfma_k16(w2of[0][1], hb1, g0);
        g0 = mfma_k16(w2of[0][2], hb2, g0); g0 = mfma_k16(w2of[0][3], hb3, g0);
        g1 = mfma_k16(w2of[1][0], hb0, g1); g1 = mfma_k16(w2of[1][1], hb1, g1);
        g1 = mfma_k16(w2of[1][2], hb2, g1); g1 = mfma_k16(w2of[1][3], hb3, g1);
        g2 = mfma_k16(w2of[2][0], hb0, g2); g2 = mfma_k16(w2of[2][1], hb1, g2);
        g2 = mfma_k16(w2of[2][2], hb2, g2); g2 = mfma_k16(w2of[2][3], hb3, g2);
        g3 = mfma_k16(w2of[3][0], hb0, g3); g3 = mfma_k16(w2of[3][1], hb1, g3);
        g3 = mfma_k16(w2of[3][2], hb2, g3); g3 = mfma_k16(w2of[3][3], hb3, g3);
        const f16x4 gb0 = relupack16(g0), gb1 = relupack16(g1);
        const f16x4 gb2 = relupack16(g2), gb3 = relupack16(g3);
        __builtin_amdgcn_sched_barrier(0);
        f16x4 w3of[2][4];
        #pragma unroll
        for (int m2 = 0; m2 < 2; ++m2)
            #pragma unroll
            for (int c = 0; c < 4; ++c)
                w3of[m2][c] = *(const f16x4*)(wsb + OFF_W3OF + ((m2*4+c)*64 + l64)*8);
        f32x4 o0 = {0.f,0.f,0.f,0.f}, o1 = {0.f,0.f,0.f,0.f};
        o0 = mfma_k16(w3of[0][0], gb0, o0); o0 = mfma_k16(w3of[0][1], gb1, o0);
        o0 = mfma_k16(w3of[0][2], gb2, o0); o0 = mfma_k16(w3of[0][3], gb3, o0);
        o1 = mfma_k16(w3of[1][0], gb0, o1); o1 = mfma_k16(w3of[1][1], gb1, o1);
        o1 = mfma_k16(w3of[1][2], gb2, o1); o1 = mfma_k16(w3of[1][3], gb3, o1);
        const float vm = (p5 < 60) ? 1.f : 0.f;
        #pragma unroll
        for (int reg = 0; reg < 4; ++reg){
            float v0 = vm * fmaxf(o0[reg], 0.f);
            v0 += __shfl_xor(v0, 1); v0 += __shfl_xor(v0, 2);
            v0 += __shfl_xor(v0, 4); v0 += __shfl_xor(v0, 8);
            float v1 = vm * fmaxf(o1[reg], 0.f);
            v1 += __shfl_xor(v1, 1); v1 += __shfl_xor(v1, 2);
            v1 += __shfl_xor(v1, 4); v1 += __shfl_xor(v1, 8);
            if (lane15 == 0){
                atomicAdd(&sf[O_F + g4 * 4 + reg], v0);
                const int oi = 16 + g4 * 4 + reg;
                if (oi < 24) atomicAdd(&sf[O_F + oi], v1);
            }
        }
    }
    __syncthreads();
    if (live && tid < 24) out[(size_t)b * 24 + tid] = sf[O_F + tid];
}

extern "C" void kernel_launch(void* const* d_in, const int* in_sizes, int n_in,
                              void* d_out, int out_size, void* d_ws, size_t ws_size,
                              hipStream_t stream) {
    const float* x      = (const float*)d_in[0];
    const float* fr_w1  = (const float*)d_in[1];
    const float* fr_b1  = (const float*)d_in[2];
    const float* fr_w2  = (const float*)d_in[3];
    const float* fr_b2  = (const float*)d_in[4];
    const float* fr_w3  = (const float*)d_in[5];
    const float* fr_b3  = (const float*)d_in[6];
    const float* fo_w1  = (const float*)d_in[7];
    const float* fo_b1  = (const float*)d_in[8];
    const float* fo_w2  = (const float*)d_in[9];
    const float* fo_b2  = (const float*)d_in[10];
    const float* fo_w3  = (const float*)d_in[11];
    const float* fo_b3  = (const float*)d_in[12];
    float* out = (float*)d_out;

    prep_kernel<<<dim3(1), dim3(64), 0, stream>>>(
        fr_w1, fr_b1, fr_w2, fr_b2, fr_w3, fr_b3,
        fo_w1, fo_b1, fo_w2, fo_b2, fo_w3, fo_b3, d_ws);

    const int B = in_sizes[0] / 1800;
    innet_kernel<<<dim3((B + 1) / 2), dim3(512), 0, stream>>>(x, d_ws, out, B);
}

// Round 17
// 149.914 us; speedup vs baseline: 1.2352x; 1.2352x over previous
//
#include <hip/hip_runtime.h>

typedef _Float16 f16x8 __attribute__((ext_vector_type(8)));
typedef _Float16 f16x4 __attribute__((ext_vector_type(4)));
typedef float  f32x4  __attribute__((ext_vector_type(4)));
typedef unsigned int u32x4 __attribute__((ext_vector_type(4)));
typedef unsigned int u32x2 __attribute__((ext_vector_type(2)));

#define MFMA32F __builtin_amdgcn_mfma_f32_16x16x32_f16

// K=16 f16 MFMA, hazard-safe
__device__ __forceinline__ f32x4 mfma_k16(const f16x4& a, const f16x4& b, f32x4 c){
#if __has_builtin(__builtin_amdgcn_mfma_f32_16x16x16f16)
    return __builtin_amdgcn_mfma_f32_16x16x16f16(a, b, c, 0, 0, 0);
#else
    asm volatile("s_nop 1\n\t"
                 "v_mfma_f32_16x16x16_f16 %0, %1, %2, %0\n\t"
                 "s_nop 7\n\t"
                 "s_nop 7"
                 : "+v"(c)
                 : "v"(__builtin_bit_cast(u32x2, a)), "v"(__builtin_bit_cast(u32x2, b)));
    return c;
#endif
}

// ---- d_ws fragment-image layout (byte offsets; lane-major 16B/8B rows) ----
#define OFF_W1AF 0
#define OFF_W1BF 4096
#define OFF_W2TF 8192
#define OFF_W3TF 16384
#define OFF_W1OF 20480
#define OFF_W2OF 28672
#define OFF_W3OF 36864
#define OFF_B1V  40960

// ---- LDS layout ----
#define XT_S 0        // Xt[60][40] f16 (cols 30..39 zero)
#define A_S  2400     // A[64][72] f16 (col60=1.0-carry, rows 60..63=0)
#define B_S  7008     // B[64][72] f16
#define EB_F 5808     // Ebar[60][20] f32 (float idx)
#define O_F  7008     // O[24] f32 (float idx)
#define NSH  14064    // 28128 B

__device__ __forceinline__ unsigned short hbits(float x){ return __builtin_bit_cast(unsigned short, (_Float16)x); }

__device__ __forceinline__ f16x8 addrelu16(u32x4 a, u32x4 b){
    f16x8 s = __builtin_bit_cast(f16x8, a) + __builtin_bit_cast(f16x8, b);
    const f16x8 z = {};
    return __builtin_elementwise_max(s, z);
}

__device__ __forceinline__ f16x4 relupack16(const f32x4& d){
    u32x2 u;
    u[0] = __builtin_bit_cast(unsigned int, __builtin_amdgcn_cvt_pkrtz(d[0], d[1]));
    u[1] = __builtin_bit_cast(unsigned int, __builtin_amdgcn_cvt_pkrtz(d[2], d[3]));
    const f16x4 z = {};
    return __builtin_elementwise_max(__builtin_bit_cast(f16x4, u), z);
}

// ---- prep kernel: materialize all weight fragments once (1 block x 64 threads) ----
__global__ void prep_kernel(const float* __restrict__ fr_w1, const float* __restrict__ fr_b1,
                            const float* __restrict__ fr_w2, const float* __restrict__ fr_b2,
                            const float* __restrict__ fr_w3, const float* __restrict__ fr_b3,
                            const float* __restrict__ fo_w1, const float* __restrict__ fo_b1,
                            const float* __restrict__ fo_w2, const float* __restrict__ fo_b2,
                            const float* __restrict__ fo_w3, const float* __restrict__ fo_b3,
                            void* __restrict__ wsv)
{
    const int l = threadIdx.x;
    if (l >= 64) return;
    const int lane15 = l & 15, g4 = (l >> 4) & 3;
    unsigned short* ws = (unsigned short*)wsv;

    for (int n = 0; n < 4; ++n){
        const int col = n * 16 + lane15;
        const bool cvv = col < 60;
        for (int j = 0; j < 8; ++j){
            const int f = g4 * 8 + j;
            ws[OFF_W1AF/2 + (n*64+l)*8 + j] = hbits((f < 30 && cvv) ? fr_w1[f*60+col] : 0.f);
            ws[OFF_W1BF/2 + (n*64+l)*8 + j] = hbits((f < 30 && cvv) ? fr_w1[(30+f)*60+col] : 0.f);
        }
    }
    for (int m = 0; m < 4; ++m){
        const int row = m * 16 + lane15;
        for (int c2 = 0; c2 < 2; ++c2)
            for (int j = 0; j < 8; ++j){
                const int k = c2*32 + g4*8 + j;
                float v = 0.f;
                if (row < 60)       v = (k < 60) ? fr_w2[k*60+row] : (k == 60 ? fr_b2[row] : 0.f);
                else if (row == 60) v = (k == 60) ? 1.f : 0.f;
                ws[OFF_W2TF/2 + ((m*2+c2)*64+l)*8 + j] = hbits(v);
            }
    }
    for (int m2 = 0; m2 < 2; ++m2){
        const int e = m2 * 16 + lane15;
        for (int c = 0; c < 4; ++c)
            for (int j = 0; j < 4; ++j){
                const int k = c*16 + g4*4 + j;
                float v = 0.f;
                if (e < 20) v = (k < 60) ? fr_w3[k*20+e] : (k == 60 ? fr_b3[e] : 0.f);
                ws[OFF_W3TF/2 + ((m2*4+c)*64+l)*4 + j] = hbits(v);
            }
    }
    for (int m = 0; m < 4; ++m){
        const int h = m * 16 + lane15;
        for (int c2 = 0; c2 < 2; ++c2)
            for (int j = 0; j < 8; ++j){
                const int k = c2*32 + g4*8 + j;
                float v = 0.f;
                if (h < 60)       v = (k < 50) ? fo_w1[k*60+h] : (k == 50 ? fo_b1[h] : 0.f);
                else if (h == 60) v = (k == 50) ? 1.f : 0.f;
                ws[OFF_W1OF/2 + ((m*2+c2)*64+l)*8 + j] = hbits(v);
            }
    }
    for (int m = 0; m < 4; ++m){
        const int h2 = m * 16 + lane15;
        for (int c = 0; c < 4; ++c)
            for (int j = 0; j < 4; ++j){
                const int k = c*16 + g4*4 + j;
                float v = 0.f;
                if (h2 < 60)       v = (k < 60) ? fo_w2[k*60+h2] : (k == 60 ? fo_b2[h2] : 0.f);
                else if (h2 == 60) v = (k == 60) ? 1.f : 0.f;
                ws[OFF_W2OF/2 + ((m*4+c)*64+l)*4 + j] = hbits(v);
            }
    }
    for (int m2 = 0; m2 < 2; ++m2){
        const int o = m2 * 16 + lane15;
        for (int c = 0; c < 4; ++c)
            for (int j = 0; j < 4; ++j){
                const int k = c*16 + g4*4 + j;
                float v = 0.f;
                if (o < 24) v = (k < 60) ? fo_w3[k*24+o] : (k == 60 ? fo_b3[o] : 0.f);
                ws[OFF_W3OF/2 + ((m2*4+c)*64+l)*4 + j] = hbits(v);
            }
    }
    float* wb = (float*)((char*)wsv + OFF_B1V);
    for (int n = 0; n < 4; ++n){
        const int col = n * 16 + lane15;
        wb[l*4 + n] = (col < 60) ? fr_b1[col] : ((col == 60) ? 1.0f : 0.0f);
    }
}

__global__ __launch_bounds__(256, 3)
void innet_kernel(const float* __restrict__ x, const void* __restrict__ wsv,
                  float* __restrict__ out)
{
    __shared__ __align__(16) unsigned short ss[NSH];
    float* sf = (float*)ss;

    const int b      = blockIdx.x;
    const int tid    = threadIdx.x;
    const int lane15 = tid & 15;
    const int g4     = (tid >> 4) & 3;
    const int w      = tid >> 6;
    const int l64    = tid & 63;
    const char* wsb  = (const char*)wsv;

    // ---- phase 0 ----
    const float* xb = x + b * 1800;
    for (int i = tid; i < 1800; i += 256){
        const int f = i / 60, p = i - f * 60;
        ss[XT_S + p * 40 + f] = hbits(xb[i]);
    }
    for (int i = tid; i < 600; i += 256){
        const int p = i / 10;
        ss[XT_S + p * 40 + 30 + (i - p * 10)] = 0;
    }
    for (int i = tid; i < 576; i += 256){
        const int arr = i / 288, rem = i - arr * 288;
        ss[(arr ? B_S : A_S) + 60 * 72 + rem] = 0;
    }
    for (int i = tid; i < 1200; i += 256) sf[EB_F + i] = 0.f;
    if (tid < 24) sf[O_F + tid] = 0.f;
    __syncthreads();

    // ---- phase 1: A/B panels via MFMA ----
    {
        f16x8 w1af[4], w1bf[4];
        #pragma unroll
        for (int n = 0; n < 4; ++n){
            w1af[n] = *(const f16x8*)(wsb + OFF_W1AF + (n*64 + l64)*16);
            w1bf[n] = *(const f16x8*)(wsb + OFF_W1BF + (n*64 + l64)*16);
        }
        const f32x4 b1v = *(const f32x4*)(wsb + OFF_B1V + l64*16);
        const int pr_ = w * 16 + lane15;
        const u32x4 ux = *(const u32x4*)&ss[XT_S + pr_ * 40 + g4 * 8];
        const f16x8 xa = __builtin_bit_cast(f16x8, ux);
        const f32x4 z = {0.f, 0.f, 0.f, 0.f};
        f32x4 aA0 = MFMA32F(xa, w1af[0], z, 0, 0, 0);
        f32x4 aA1 = MFMA32F(xa, w1af[1], z, 0, 0, 0);
        f32x4 aA2 = MFMA32F(xa, w1af[2], z, 0, 0, 0);
        f32x4 aA3 = MFMA32F(xa, w1af[3], z, 0, 0, 0);
        f32x4 aB0 = MFMA32F(xa, w1bf[0], z, 0, 0, 0);
        f32x4 aB1 = MFMA32F(xa, w1bf[1], z, 0, 0, 0);
        f32x4 aB2 = MFMA32F(xa, w1bf[2], z, 0, 0, 0);
        f32x4 aB3 = MFMA32F(xa, w1bf[3], z, 0, 0, 0);
        #pragma unroll
        for (int reg = 0; reg < 4; ++reg){
            const int p = w * 16 + g4 * 4 + reg;
            if (p < 60){
                ss[A_S + p * 72 +      lane15] = hbits(aA0[reg] + b1v[0]);
                ss[A_S + p * 72 + 16 + lane15] = hbits(aA1[reg] + b1v[1]);
                ss[A_S + p * 72 + 32 + lane15] = hbits(aA2[reg] + b1v[2]);
                ss[A_S + p * 72 + 48 + lane15] = hbits(aA3[reg] + b1v[3]);
                ss[B_S + p * 72 +      lane15] = hbits(aB0[reg]);
                ss[B_S + p * 72 + 16 + lane15] = hbits(aB1[reg]);
                ss[B_S + p * 72 + 32 + lane15] = hbits(aB2[reg]);
                ss[B_S + p * 72 + 48 + lane15] = hbits(aB3[reg]);
            }
        }
    }
    __syncthreads();

    // ---- phase 2: swapped register chain. wave w owns receivers r = w, w+4, ... ----
    {
        f16x8 w2tf[4][2];
        #pragma unroll
        for (int m = 0; m < 4; ++m)
            #pragma unroll
            for (int c2 = 0; c2 < 2; ++c2)
                w2tf[m][c2] = *(const f16x8*)(wsb + OFF_W2TF + ((m*2+c2)*64 + l64)*16);
        f16x4 w3tf[2][4];
        #pragma unroll
        for (int m2 = 0; m2 < 2; ++m2)
            #pragma unroll
            for (int c = 0; c < 4; ++c)
                w3tf[m2][c] = *(const f16x4*)(wsb + OFF_W3TF + ((m2*4+c)*64 + l64)*8);

        #pragma unroll 1
        for (int r = w; r < 60; r += 4){
            const u32x4 a0 = *(const u32x4*)&ss[A_S + r * 72 + g4 * 8];
            const u32x4 a1 = *(const u32x4*)&ss[A_S + r * 72 + 32 + g4 * 8];
            f32x4 acc0 = {0.f,0.f,0.f,0.f}, acc1 = {0.f,0.f,0.f,0.f};
            #pragma unroll
            for (int st = 0; st < 4; ++st){
                const int s = st * 16 + lane15;
                const u32x4 bb0 = *(const u32x4*)&ss[B_S + s * 72 + g4 * 8];
                const u32x4 bb1 = *(const u32x4*)&ss[B_S + s * 72 + 32 + g4 * 8];
                const f16x8 h0 = addrelu16(a0, bb0);
                const f16x8 h1 = addrelu16(a1, bb1);
                __builtin_amdgcn_s_setprio(1);
                f32x4 d0 = {0.f,0.f,0.f,0.f}, d1 = {0.f,0.f,0.f,0.f};
                f32x4 d2 = {0.f,0.f,0.f,0.f}, d3 = {0.f,0.f,0.f,0.f};
                d0 = MFMA32F(w2tf[0][0], h0, d0, 0,0,0); d0 = MFMA32F(w2tf[0][1], h1, d0, 0,0,0);
                d1 = MFMA32F(w2tf[1][0], h0, d1, 0,0,0); d1 = MFMA32F(w2tf[1][1], h1, d1, 0,0,0);
                d2 = MFMA32F(w2tf[2][0], h0, d2, 0,0,0); d2 = MFMA32F(w2tf[2][1], h1, d2, 0,0,0);
                d3 = MFMA32F(w2tf[3][0], h0, d3, 0,0,0); d3 = MFMA32F(w2tf[3][1], h1, d3, 0,0,0);
                const f16x4 hb0 = relupack16(d0), hb1 = relupack16(d1);
                const f16x4 hb2 = relupack16(d2), hb3 = relupack16(d3);
                f32x4 e0 = {0.f,0.f,0.f,0.f}, e1 = {0.f,0.f,0.f,0.f};
                e0 = mfma_k16(w3tf[0][0], hb0, e0); e0 = mfma_k16(w3tf[0][1], hb1, e0);
                e0 = mfma_k16(w3tf[0][2], hb2, e0); e0 = mfma_k16(w3tf[0][3], hb3, e0);
                e1 = mfma_k16(w3tf[1][0], hb0, e1); e1 = mfma_k16(w3tf[1][1], hb1, e1);
                e1 = mfma_k16(w3tf[1][2], hb2, e1); e1 = mfma_k16(w3tf[1][3], hb3, e1);
                __builtin_amdgcn_s_setprio(0);
                const float vm = (s < 60 && s != r) ? 1.f : 0.f;
                #pragma unroll
                for (int reg = 0; reg < 4; ++reg){
                    acc0[reg] += vm * fmaxf(e0[reg], 0.f);
                    acc1[reg] += vm * fmaxf(e1[reg], 0.f);
                }
            }
            #pragma unroll
            for (int reg = 0; reg < 4; ++reg){
                float v0 = acc0[reg];
                v0 += __shfl_xor(v0, 1); v0 += __shfl_xor(v0, 2);
                v0 += __shfl_xor(v0, 4); v0 += __shfl_xor(v0, 8);
                float v1 = acc1[reg];
                v1 += __shfl_xor(v1, 1); v1 += __shfl_xor(v1, 2);
                v1 += __shfl_xor(v1, 4); v1 += __shfl_xor(v1, 8);
                if (lane15 == 0){
                    sf[EB_F + r * 20 + g4 * 4 + reg] += v0;
                    const int e1i = 16 + g4 * 4 + reg;
                    if (e1i < 20) sf[EB_F + r * 20 + e1i] += v1;
                }
            }
        }
    }
    __syncthreads();

    // ---- phase 5: output MLP, swapped chain ----
    {
        const int p5 = w * 16 + lane15;
        const int pe = (p5 < 60) ? p5 : 0;
        const u32x4 uc0 = *(const u32x4*)&ss[XT_S + pe * 40 + g4 * 8];
        f16x8 cb0 = __builtin_bit_cast(f16x8, uc0);
        if (g4 == 3){
            cb0[6] = (_Float16)sf[EB_F + pe * 20 + 0];
            cb0[7] = (_Float16)sf[EB_F + pe * 20 + 1];
        }
        f16x8 cb1;
        #pragma unroll
        for (int j = 0; j < 8; ++j){
            const int k = 32 + g4 * 8 + j;
            float v;
            if (k < 50) v = sf[EB_F + pe * 20 + (k - 30)];
            else        v = (k == 50) ? 1.f : 0.f;
            cb1[j] = (_Float16)v;
        }
        f16x8 w1of[4][2];
        #pragma unroll
        for (int m = 0; m < 4; ++m)
            #pragma unroll
            for (int c2 = 0; c2 < 2; ++c2)
                w1of[m][c2] = *(const f16x8*)(wsb + OFF_W1OF + ((m*2+c2)*64 + l64)*16);
        f32x4 d0 = {0.f,0.f,0.f,0.f}, d1 = {0.f,0.f,0.f,0.f};
        f32x4 d2 = {0.f,0.f,0.f,0.f}, d3 = {0.f,0.f,0.f,0.f};
        d0 = MFMA32F(w1of[0][0], cb0, d0, 0,0,0); d0 = MFMA32F(w1of[0][1], cb1, d0, 0,0,0);
        d1 = MFMA32F(w1of[1][0], cb0, d1, 0,0,0); d1 = MFMA32F(w1of[1][1], cb1, d1, 0,0,0);
        d2 = MFMA32F(w1of[2][0], cb0, d2, 0,0,0); d2 = MFMA32F(w1of[2][1], cb1, d2, 0,0,0);
        d3 = MFMA32F(w1of[3][0], cb0, d3, 0,0,0); d3 = MFMA32F(w1of[3][1], cb1, d3, 0,0,0);
        const f16x4 hb0 = relupack16(d0), hb1 = relupack16(d1);
        const f16x4 hb2 = relupack16(d2), hb3 = relupack16(d3);
        __builtin_amdgcn_sched_barrier(0);
        f16x4 w2of[4][4];
        #pragma unroll
        for (int m = 0; m < 4; ++m)
            #pragma unroll
            for (int c = 0; c < 4; ++c)
                w2of[m][c] = *(const f16x4*)(wsb + OFF_W2OF + ((m*4+c)*64 + l64)*8);
        f32x4 g0 = {0.f,0.f,0.f,0.f}, g1 = {0.f,0.f,0.f,0.f};
        f32x4 g2 = {0.f,0.f,0.f,0.f}, g3 = {0.f,0.f,0.f,0.f};
        g0 = mfma_k16(w2of[0][0], hb0, g0); g0 = mfma_k16(w2of[0][1], hb1, g0);
        g0 = mfma_k16(w2of[0][2], hb2, g0); g0 = mfma_k16(w2of[0][3], hb3, g0);
        g1 = mfma_k16(w2of[1][0], hb0, g1); g1 = mfma_k16(w2of[1][1], hb1, g1);
        g1 = mfma_k16(w2of[1][2], hb2, g1); g1 = mfma_k16(w2of[1][3], hb3, g1);
        g2 = mfma_k16(w2of[2][0], hb0, g2); g2 = mfma_k16(w2of[2][1], hb1, g2);
        g2 = mfma_k16(w2of[2][2], hb2, g2); g2 = mfma_k16(w2of[2][3], hb3, g2);
        g3 = mfma_k16(w2of[3][0], hb0, g3); g3 = mfma_k16(w2of[3][1], hb1, g3);
        g3 = mfma_k16(w2of[3][2], hb2, g3); g3 = mfma_k16(w2of[3][3], hb3, g3);
        const f16x4 gb0 = relupack16(g0), gb1 = relupack16(g1);
        const f16x4 gb2 = relupack16(g2), gb3 = relupack16(g3);
        __builtin_amdgcn_sched_barrier(0);
        f16x4 w3of[2][4];
        #pragma unroll
        for (int m2 = 0; m2 < 2; ++m2)
            #pragma unroll
            for (int c = 0; c < 4; ++c)
                w3of[m2][c] = *(const f16x4*)(wsb + OFF_W3OF + ((m2*4+c)*64 + l64)*8);
        f32x4 o0 = {0.f,0.f,0.f,0.f}, o1 = {0.f,0.f,0.f,0.f};
        o0 = mfma_k16(w3of[0][0], gb0, o0); o0 = mfma_k16(w3of[0][1], gb1, o0);
        o0 = mfma_k16(w3of[0][2], gb2, o0); o0 = mfma_k16(w3of[0][3], gb3, o0);
        o1 = mfma_k16(w3of[1][0], gb0, o1); o1 = mfma_k16(w3of[1][1], gb1, o1);
        o1 = mfma_k16(w3of[1][2], gb2, o1); o1 = mfma_k16(w3of[1][3], gb3, o1);
        const float vm = (p5 < 60) ? 1.f : 0.f;
        #pragma unroll
        for (int reg = 0; reg < 4; ++reg){
            float v0 = vm * fmaxf(o0[reg], 0.f);
            v0 += __shfl_xor(v0, 1); v0 += __shfl_xor(v0, 2);
            v0 += __shfl_xor(v0, 4); v0 += __shfl_xor(v0, 8);
            float v1 = vm * fmaxf(o1[reg], 0.f);
            v1 += __shfl_xor(v1, 1); v1 += __shfl_xor(v1, 2);
            v1 += __shfl_xor(v1, 4); v1 += __shfl_xor(v1, 8);
            if (lane15 == 0){
                atomicAdd(&sf[O_F + g4 * 4 + reg], v0);
                const int oi = 16 + g4 * 4 + reg;
                if (oi < 24) atomicAdd(&sf[O_F + oi], v1);
            }
        }
    }
    __syncthreads();
    if (tid < 24) out[(size_t)b * 24 + tid] = sf[O_F + tid];
}

extern "C" void kernel_launch(void* const* d_in, const int* in_sizes, int n_in,
                              void* d_out, int out_size, void* d_ws, size_t ws_size,
                              hipStream_t stream) {
    const float* x      = (const float*)d_in[0];
    const float* fr_w1  = (const float*)d_in[1];
    const float* fr_b1  = (const float*)d_in[2];
    const float* fr_w2  = (const float*)d_in[3];
    const float* fr_b2  = (const float*)d_in[4];
    const float* fr_w3  = (const float*)d_in[5];
    const float* fr_b3  = (const float*)d_in[6];
    const float* fo_w1  = (const float*)d_in[7];
    const float* fo_b1  = (const float*)d_in[8];
    const float* fo_w2  = (const float*)d_in[9];
    const float* fo_b2  = (const float*)d_in[10];
    const float* fo_w3  = (const float*)d_in[11];
    const float* fo_b3  = (const float*)d_in[12];
    float* out = (float*)d_out;

    prep_kernel<<<dim3(1), dim3(64), 0, stream>>>(
        fr_w1, fr_b1, fr_w2, fr_b2, fr_w3, fr_b3,
        fo_w1, fo_b1, fo_w2, fo_b2, fo_w3, fo_b3, d_ws);

    const int B = in_sizes[0] / 1800;
    innet_kernel<<<dim3(B), dim3(256), 0, stream>>>(x, d_ws, out);
}